// Round 5
// baseline (6732.558 us; speedup 1.0000x reference)
//
#include <hip/hip_runtime.h>
#include <hip/hip_bf16.h>

// Sumformer inner block: 9-GEMM bf16 MFMA pipeline + segment-mean + gather.
// R5: ROOT CAUSE FIX -- psi_Wo was never converted to bf16 (missing wt_conv
// since R0); final GEMM read uninitialized ws as bf16. Added the conversion.
// Sentinel codes now code*1e8+CH so they dominate any garbage. Full on-device
// self-check retained this round (strip next round once green).
// Fault codes (out[0] = code*1e8+CH): 1=CH0, 2=final-gemm, 3=gather/sh-chain,
// 4=hidden-gemm, 5=sigma, 6=conversions.

typedef __attribute__((ext_vector_type(8))) short bf16x8;
typedef __attribute__((ext_vector_type(4))) float f32x4;

#define N_NODES 131072
#define NUM_G   1024

__device__ __forceinline__ float lrelu_f(float v) { return v >= 0.f ? v : 0.01f * v; }
__device__ __forceinline__ float bf2f(__hip_bfloat16 h) { return __bfloat162float(h); }

__global__ void sentinel(float* out, float v) {
  if (blockIdx.x == 0 && threadIdx.x == 0) out[0] = v;
}

// WT[p][k] = bf16(W[k][p]);  W is [K][P]
__global__ void wt_conv(const float* __restrict__ W, __hip_bfloat16* __restrict__ WT, int K, int P) {
  int idx = blockIdx.x * 256 + threadIdx.x;
  if (idx >= K * P) return;
  int p = idx / K;
  int k = idx - p * K;
  WT[idx] = __float2bfloat16(W[(size_t)k * P + p]);
}

__global__ void xconv(const float* __restrict__ x, __hip_bfloat16* __restrict__ xb, int n4) {
  int i = blockIdx.x * 256 + threadIdx.x;
  if (i >= n4) return;
  float4 v = reinterpret_cast<const float4*>(x)[i];
  union { __hip_bfloat16 h[4]; uint2 u; } o;
  o.h[0] = __float2bfloat16(v.x); o.h[1] = __float2bfloat16(v.y);
  o.h[2] = __float2bfloat16(v.z); o.h[3] = __float2bfloat16(v.w);
  reinterpret_cast<uint2*>(xb)[i] = o.u;
}

template<int FIRST>
__global__ void seg_accum(const __hip_bfloat16* __restrict__ nechunk,
                          const int* __restrict__ ids,
                          float* __restrict__ sums, int rb, int ch) {
  int g = blockIdx.x;
  int k = threadIdx.x;
  int lo = 0, hi = N_NODES;
  while (lo < hi) { int m = (lo + hi) >> 1; if (ids[m] < g) lo = m + 1; else hi = m; }
  int s = lo;
  hi = N_NODES;
  while (lo < hi) { int m = (lo + hi) >> 1; if (ids[m] < g + 1) lo = m + 1; else hi = m; }
  int e = lo;
  int s2 = s > rb ? s : rb;
  int e2 = e < rb + ch ? e : rb + ch;
  float acc = 0.f;
  for (int r = s2; r < e2; ++r)
    acc += bf2f(nechunk[(size_t)(r - rb) * 256 + k]);
  if (FIRST) sums[g * 256 + k] = acc;
  else if (e2 > s2) sums[g * 256 + k] += acc;
}

__global__ void sigma_fin(const float* __restrict__ sums,
                          const int* __restrict__ ids,
                          __hip_bfloat16* __restrict__ sigma) {
  int g = blockIdx.x;
  int k = threadIdx.x;
  int lo = 0, hi = N_NODES;
  while (lo < hi) { int m = (lo + hi) >> 1; if (ids[m] < g) lo = m + 1; else hi = m; }
  int s = lo;
  hi = N_NODES;
  while (lo < hi) { int m = (lo + hi) >> 1; if (ids[m] < g + 1) lo = m + 1; else hi = m; }
  int e = lo;
  float c = (float)(e - s);
  sigma[g * 256 + k] = __float2bfloat16(sums[g * 256 + k] / fmaxf(c, 1.f));
}

// Fused GEMM: out[M,P] = act(A[M,K] @ BT[P,K]^T + bias (+ extra[bids[row]]))
// 128x128 tile, 4 waves (2x2 of 64x64), BK=64, mfma_f32_16x16x32_bf16.
// Reg-staged: global dwordx4 -> register -> XOR-swizzled ds_write_b128
// (write-side swizzle == read-side swizzle, same expression).
template<int ACT, int BF16OUT, int ADD_EXTRA>
__global__ __launch_bounds__(256)
void gemm_mfma(const __hip_bfloat16* __restrict__ A,
               const __hip_bfloat16* __restrict__ BT,
               const float* __restrict__ bias,
               const float* __restrict__ extra,
               const int* __restrict__ bids,
               void* __restrict__ out,
               int K, int P) {
  __shared__ __attribute__((aligned(16))) char smemA[16384];
  __shared__ __attribute__((aligned(16))) char smemB[16384];

  const int tid  = threadIdx.x;
  const int lane = tid & 63;
  const int wave = tid >> 6;
  const int brow = blockIdx.x << 7;
  const int bcol = blockIdx.y << 7;
  const int wm = (wave >> 1) << 6;
  const int wn = (wave & 1) << 6;

  f32x4 acc[4][4] = {};

  for (int k0 = 0; k0 < K; k0 += 64) {
    bf16x8 ra[4], rbv[4];
#pragma unroll
    for (int i = 0; i < 4; ++i) {
      int f = (i << 8) + tid;   // 0..1023: row = f>>3 (0..127), chunk = f&7
      int row = f >> 3, ch = f & 7;
      ra[i]  = *reinterpret_cast<const bf16x8*>(A  + (size_t)(brow + row) * K + k0 + (ch << 3));
      rbv[i] = *reinterpret_cast<const bf16x8*>(BT + (size_t)(bcol + row) * K + k0 + (ch << 3));
    }
    if (k0) __syncthreads();   // all waves done reading previous tile
#pragma unroll
    for (int i = 0; i < 4; ++i) {
      int f = (i << 8) + tid;
      int row = f >> 3, ch = f & 7;
      int sw = (ch ^ (row & 7)) << 4;
      *reinterpret_cast<bf16x8*>(smemA + row * 128 + sw) = ra[i];
      *reinterpret_cast<bf16x8*>(smemB + row * 128 + sw) = rbv[i];
    }
    __syncthreads();

    const int r15 = lane & 15;
#pragma unroll
    for (int ks = 0; ks < 2; ++ks) {
      const int c = (ks << 2) + (lane >> 4);  // logical k-chunk 0..7
      bf16x8 af[4], bfv[4];
#pragma unroll
      for (int f = 0; f < 4; ++f) {
        int ar = wm + (f << 4) + r15;
        af[f]  = *reinterpret_cast<const bf16x8*>(smemA + ar * 128 + ((c ^ (ar & 7)) << 4));
        int br = wn + (f << 4) + r15;
        bfv[f] = *reinterpret_cast<const bf16x8*>(smemB + br * 128 + ((c ^ (br & 7)) << 4));
      }
#pragma unroll
      for (int fm = 0; fm < 4; ++fm)
#pragma unroll
        for (int fn = 0; fn < 4; ++fn)
          acc[fm][fn] = __builtin_amdgcn_mfma_f32_16x16x32_bf16(af[fm], bfv[fn], acc[fm][fn], 0, 0, 0);
    }
  }

  // epilogue: C/D layout col=lane&15, row=(lane>>4)*4+reg   [m89-verified]
  const int r15 = lane & 15;
  const int hi4 = (lane >> 4) << 2;
#pragma unroll
  for (int fn = 0; fn < 4; ++fn) {
    int col = bcol + wn + (fn << 4) + r15;
    float bv = bias[col];
#pragma unroll
    for (int fm = 0; fm < 4; ++fm) {
      int row0 = brow + wm + (fm << 4) + hi4;
#pragma unroll
      for (int r = 0; r < 4; ++r) {
        float v = acc[fm][fn][r] + bv;
        if (ADD_EXTRA) {
          int b = bids[row0 + r];
          v += extra[(size_t)b * P + col];
        }
        if (ACT) v = lrelu_f(v);
        size_t oidx = (size_t)(row0 + r) * P + col;
        if (BF16OUT) reinterpret_cast<__hip_bfloat16*>(out)[oidx] = __float2bfloat16(v);
        else         reinterpret_cast<float*>(out)[oidx] = v;
      }
    }
  }
}

// Self-check: on failure writes code*1e8+CH into out[0] (dominates garbage).
__global__ __launch_bounds__(256) void checker(
    const float* __restrict__ x, const int* __restrict__ ids,
    const float* geW0, const float* geb0, const float* geWh, const float* gebh,
    const float* geWo, const float* gebo,
    const float* inW, const float* inb, const float* agW, const float* agb,
    const float* psiWh, const float* psibh, const float* psiWo, const float* psibo,
    const __hip_bfloat16* xc, const __hip_bfloat16* pp0, const __hip_bfloat16* pp1,
    const __hip_bfloat16* psiWh2T, const __hip_bfloat16* psiWoT,
    const __hip_bfloat16* sigma,
    float* out, int CH) {
  __shared__ float sA[512], sB[512], sAcc[256];
  __shared__ int sFlag, sE;
  const int tid = threadIdx.x;
  if (tid == 0) {
    sFlag = 0;
    int g = ids[0];
    int lo = 0, hi = N_NODES;
    while (lo < hi) { int m = (lo + hi) >> 1; if (ids[m] < g + 1) lo = m + 1; else hi = m; }
    sE = lo;   // rows 0..sE-1 belong to graph ids[0]
  }
  __syncthreads();

  // A0: conversions (exact bf16 equality; same RNE op on both sides)
  if (tid < 128) {
    if (bf2f(psiWoT[(size_t)tid * 512 + 7]) != bf2f(__float2bfloat16(psiWo[(size_t)7 * 128 + tid])))
      atomicOr(&sFlag, 1);
    if (bf2f(xc[tid]) != bf2f(__float2bfloat16(x[(size_t)(N_NODES - CH) * 128 + tid])))
      atomicOr(&sFlag, 1);
  }

  // A: final gemm rows 0,1 of last chunk vs serial fp32 on same bf16 operands
  if (tid < 128) {
    for (int r = 0; r < 2; ++r) {
      float s = psibo[tid];
      for (int k = 0; k < 512; ++k)
        s += bf2f(pp1[(size_t)r * 512 + k]) * bf2f(psiWoT[(size_t)tid * 512 + k]);
      float dv = out[(size_t)(N_NODES - CH + r) * 128 + tid];
      if (fabsf(dv - s) > 5e-5f + 0.005f * fabsf(s)) atomicOr(&sFlag, 2);
    }
  }

  // B: p2 -> p3 gemm (row 0 of last chunk) vs stored bf16 pp1
  for (int c = tid; c < 512; c += 256) {
    float s = psibh[1024 + c];
    for (int k = 0; k < 512; ++k)
      s += bf2f(pp0[k]) * bf2f(psiWh2T[(size_t)c * 512 + k]);
    s = lrelu_f(s);
    if (fabsf(bf2f(pp1[c]) - s) > 5e-4f + 0.02f * fabsf(s)) atomicOr(&sFlag, 4);
  }
  __syncthreads();

  // C: sigma of graph ids[0] via full fp32 chain
  sAcc[tid] = 0.f;
  __syncthreads();
  const int e = sE;
  for (int r = 0; r < e; ++r) {
    const float* xr = x + (size_t)r * 128;
    for (int c = tid; c < 512; c += 256) {
      float a = geb0[c];
      for (int k = 0; k < 128; ++k) a += xr[k] * geW0[(size_t)k * 512 + c];
      sA[c] = lrelu_f(a);
    }
    __syncthreads();
    for (int c = tid; c < 512; c += 256) {
      float a = gebh[c];
      for (int k = 0; k < 512; ++k) a += sA[k] * geWh[(size_t)k * 512 + c];
      sB[c] = lrelu_f(a);
    }
    __syncthreads();
    for (int c = tid; c < 512; c += 256) {
      float a = gebh[512 + c];
      for (int k = 0; k < 512; ++k) a += sB[k] * geWh[262144 + (size_t)k * 512 + c];
      sA[c] = lrelu_f(a);
    }
    __syncthreads();
    {
      float a = gebo[tid];
      for (int k = 0; k < 512; ++k) a += sA[k] * geWo[(size_t)k * 256 + tid];
      sAcc[tid] += lrelu_f(a);
    }
    __syncthreads();
  }
  {
    float sref = sAcc[tid] / fmaxf((float)e, 1.f);
    float dv = bf2f(sigma[(size_t)ids[0] * 256 + tid]);
    if (fabsf(dv - sref) > 5e-4f + 0.08f * fabsf(sref)) atomicOr(&sFlag, 8);
    sAcc[tid] = sref;
  }
  __syncthreads();

  // D: full fp32 chain for out row 0
  for (int c = tid; c < 512; c += 256) {
    float a = inb[c];
    for (int k = 0; k < 128; ++k) a += x[k] * inW[(size_t)k * 512 + c];
    float b = agb[c];
    for (int k = 0; k < 256; ++k) b += sAcc[k] * agW[(size_t)k * 512 + c];
    sA[c] = lrelu_f(a + b);
  }
  __syncthreads();
  for (int L = 0; L < 3; ++L) {
    float* pin  = (L & 1) ? sB : sA;
    float* pout = (L & 1) ? sA : sB;
    for (int c = tid; c < 512; c += 256) {
      float a = psibh[L * 512 + c];
      for (int k = 0; k < 512; ++k) a += pin[k] * psiWh[(size_t)L * 262144 + (size_t)k * 512 + c];
      pout[c] = lrelu_f(a);
    }
    __syncthreads();
  }
  if (tid < 128) {   // p3 ended in sB
    float a = psibo[tid];
    for (int k = 0; k < 512; ++k) a += sB[k] * psiWo[(size_t)k * 128 + tid];
    if (fabsf(out[tid] - a) > 3e-4f) atomicOr(&sFlag, 16);
  }
  __syncthreads();
  if (tid == 0 && sFlag) {
    int code = (sFlag & 1) ? 6 : (sFlag & 2) ? 2 : (sFlag & 4) ? 4 : (sFlag & 8) ? 5 : 3;
    out[0] = (float)code * 100000000.f + (float)CH;
  }
}

extern "C" void kernel_launch(void* const* d_in, const int* in_sizes, int n_in,
                              void* d_out, int out_size, void* d_ws, size_t ws_size,
                              hipStream_t stream) {
  const float* x      = (const float*)d_in[0];
  const int*   bids   = (const int*)  d_in[1];
  const float* ge_W0  = (const float*)d_in[2];
  const float* ge_b0  = (const float*)d_in[3];
  const float* ge_Wh  = (const float*)d_in[4];
  const float* ge_bh  = (const float*)d_in[5];
  const float* ge_Wo  = (const float*)d_in[6];
  const float* ge_bo  = (const float*)d_in[7];
  const float* in_W   = (const float*)d_in[8];
  const float* in_b   = (const float*)d_in[9];
  const float* ag_W   = (const float*)d_in[10];
  const float* ag_b   = (const float*)d_in[11];
  const float* psi_Wh = (const float*)d_in[12];
  const float* psi_bh = (const float*)d_in[13];
  const float* psi_Wo = (const float*)d_in[14];
  const float* psi_bo = (const float*)d_in[15];

  char* ws = (char*)d_ws;
  __hip_bfloat16* geW0T   = (__hip_bfloat16*)(ws + 0);        // [512][128]
  __hip_bfloat16* geWh0T  = (__hip_bfloat16*)(ws + 131072);   // [512][512]
  __hip_bfloat16* geWh1T  = (__hip_bfloat16*)(ws + 655360);   // [512][512]
  __hip_bfloat16* geWoT   = (__hip_bfloat16*)(ws + 1179648);  // [256][512]
  __hip_bfloat16* inWT    = (__hip_bfloat16*)(ws + 1441792);  // [512][128]
  __hip_bfloat16* agWT    = (__hip_bfloat16*)(ws + 1572864);  // [512][256]
  __hip_bfloat16* psiWh0T = (__hip_bfloat16*)(ws + 1835008);  // [512][512]
  __hip_bfloat16* psiWh1T = (__hip_bfloat16*)(ws + 2359296);  // [512][512]
  __hip_bfloat16* psiWh2T = (__hip_bfloat16*)(ws + 2883584);  // [512][512]
  __hip_bfloat16* psiWoT  = (__hip_bfloat16*)(ws + 3407872);  // [128][512]
  __hip_bfloat16* sigma   = (__hip_bfloat16*)(ws + 3538944);  // [1024][256] bf16
  float*          sh      = (float*)         (ws + 4063232);  // [1024][512] f32
  float*          sums    = (float*)         (ws + 6160384);  // [1024][256] f32
  const size_t base = 7340032;  // 7 MiB

  size_t CH = 0;
  {
    const size_t cands[10] = {65536, 32768, 16384, 8192, 4096, 2048, 1024, 512, 256, 128};
    for (int i = 0; i < 10; ++i)
      if (ws_size >= base + cands[i] * 2304ull) { CH = cands[i]; break; }
  }
  if (CH == 0) {
    sentinel<<<1, 64, 0, stream>>>((float*)d_out, 100000000.f + (float)(ws_size / 1024));
    return;
  }

  __hip_bfloat16* xc  = (__hip_bfloat16*)(ws + base);
  __hip_bfloat16* pp0 = (__hip_bfloat16*)(ws + base + CH * 256);
  __hip_bfloat16* pp1 = (__hip_bfloat16*)(ws + base + CH * 256 + CH * 1024);

  dim3 blk(256);
  const int nch = (int)(N_NODES / CH);
  dim3 g4((unsigned)(CH >> 7), 4), g2((unsigned)(CH >> 7), 2), g1((unsigned)(CH >> 7), 1);

  // ---- weight conversions: ALL TEN (R4 bug: psi_Wo was missing) ----
  wt_conv<<<256,  blk, 0, stream>>>(ge_W0,            geW0T,   128, 512);
  wt_conv<<<1024, blk, 0, stream>>>(ge_Wh,            geWh0T,  512, 512);
  wt_conv<<<1024, blk, 0, stream>>>(ge_Wh + 262144,   geWh1T,  512, 512);
  wt_conv<<<512,  blk, 0, stream>>>(ge_Wo,            geWoT,   512, 256);
  wt_conv<<<256,  blk, 0, stream>>>(in_W,             inWT,    128, 512);
  wt_conv<<<512,  blk, 0, stream>>>(ag_W,             agWT,    256, 512);
  wt_conv<<<1024, blk, 0, stream>>>(psi_Wh,           psiWh0T, 512, 512);
  wt_conv<<<1024, blk, 0, stream>>>(psi_Wh + 262144,  psiWh1T, 512, 512);
  wt_conv<<<1024, blk, 0, stream>>>(psi_Wh + 524288,  psiWh2T, 512, 512);
  wt_conv<<<256,  blk, 0, stream>>>(psi_Wo,           psiWoT,  512, 128);  // THE FIX

  for (int c = 0; c < nch; ++c) {
    const size_t rb = (size_t)c * CH;
    xconv<<<(unsigned)(CH >> 3), blk, 0, stream>>>(x + rb * 128, xc, (int)(CH * 32));
    gemm_mfma<1,1,0><<<g4, blk, 0, stream>>>(xc,  geW0T,  ge_b0,     nullptr, nullptr, pp0, 128, 512);
    gemm_mfma<1,1,0><<<g4, blk, 0, stream>>>(pp0, geWh0T, ge_bh,     nullptr, nullptr, pp1, 512, 512);
    gemm_mfma<1,1,0><<<g4, blk, 0, stream>>>(pp1, geWh1T, ge_bh+512, nullptr, nullptr, pp0, 512, 512);
    gemm_mfma<1,1,0><<<g2, blk, 0, stream>>>(pp0, geWoT,  ge_bo,     nullptr, nullptr, pp1, 512, 256);
    if (c == 0) seg_accum<1><<<NUM_G, blk, 0, stream>>>(pp1, bids, sums, (int)rb, (int)CH);
    else        seg_accum<0><<<NUM_G, blk, 0, stream>>>(pp1, bids, sums, (int)rb, (int)CH);
  }

  sigma_fin<<<NUM_G, blk, 0, stream>>>(sums, bids, sigma);
  gemm_mfma<0,0,0><<<dim3(8,4), blk, 0, stream>>>(sigma, agWT, ag_b, nullptr, nullptr, sh, 256, 512);

  for (int c = 0; c < nch; ++c) {
    const size_t rb = (size_t)c * CH;
    xconv<<<(unsigned)(CH >> 3), blk, 0, stream>>>(x + rb * 128, xc, (int)(CH * 32));
    gemm_mfma<1,1,1><<<g4, blk, 0, stream>>>(xc,  inWT,    in_b,        sh,      bids + rb, pp0, 128, 512);
    gemm_mfma<1,1,0><<<g4, blk, 0, stream>>>(pp0, psiWh0T, psi_bh,      nullptr, nullptr,   pp1, 512, 512);
    gemm_mfma<1,1,0><<<g4, blk, 0, stream>>>(pp1, psiWh1T, psi_bh+512,  nullptr, nullptr,   pp0, 512, 512);
    gemm_mfma<1,1,0><<<g4, blk, 0, stream>>>(pp0, psiWh2T, psi_bh+1024, nullptr, nullptr,   pp1, 512, 512);
    gemm_mfma<0,0,0><<<g1, blk, 0, stream>>>(pp1, psiWoT,  psi_bo,      nullptr, nullptr,
                                             (float*)d_out + rb * 128, 512, 128);
  }

  checker<<<1, blk, 0, stream>>>(x, bids,
      ge_W0, ge_b0, ge_Wh, ge_bh, ge_Wo, ge_bo,
      in_W, in_b, ag_W, ag_b, psi_Wh, psi_bh, psi_Wo, psi_bo,
      xc, pp0, pp1, psiWh2T, psiWoT, sigma, (float*)d_out, (int)CH);
}

// Round 6
// 1013.582 us; speedup vs baseline: 6.6423x; 6.6423x over previous
//
#include <hip/hip_runtime.h>
#include <hip/hip_bf16.h>

// Sumformer inner block: 9-GEMM bf16 MFMA pipeline + segment-mean + gather.
// R6: checker removed (was 5.83ms of 6.73ms); staging restored to
// global_load_lds width=16 (R3's path -- re-audited correct; R2/R3 failures
// were solely the missing psi_Wo conversion fixed in R5).
// Swizzle invariant: LDS chunk j of row r holds global chunk j^(r&7);
// read of logical chunk c fetches LDS chunk c^(r&7). Verified green in R5
// with the equivalent reg-staged writer.

typedef __attribute__((ext_vector_type(8))) short bf16x8;
typedef __attribute__((ext_vector_type(4))) float f32x4;

#define N_NODES 131072
#define NUM_G   1024

__device__ __forceinline__ float lrelu_f(float v) { return v >= 0.f ? v : 0.01f * v; }
__device__ __forceinline__ float bf2f(__hip_bfloat16 h) { return __bfloat162float(h); }

__global__ void sentinel(float* out, float v) {
  if (blockIdx.x == 0 && threadIdx.x == 0) out[0] = v;
}

// WT[p][k] = bf16(W[k][p]);  W is [K][P]
__global__ void wt_conv(const float* __restrict__ W, __hip_bfloat16* __restrict__ WT, int K, int P) {
  int idx = blockIdx.x * 256 + threadIdx.x;
  if (idx >= K * P) return;
  int p = idx / K;
  int k = idx - p * K;
  WT[idx] = __float2bfloat16(W[(size_t)k * P + p]);
}

__global__ void xconv(const float* __restrict__ x, __hip_bfloat16* __restrict__ xb, int n4) {
  int i = blockIdx.x * 256 + threadIdx.x;
  if (i >= n4) return;
  float4 v = reinterpret_cast<const float4*>(x)[i];
  union { __hip_bfloat16 h[4]; uint2 u; } o;
  o.h[0] = __float2bfloat16(v.x); o.h[1] = __float2bfloat16(v.y);
  o.h[2] = __float2bfloat16(v.z); o.h[3] = __float2bfloat16(v.w);
  reinterpret_cast<uint2*>(xb)[i] = o.u;
}

template<int FIRST>
__global__ void seg_accum(const __hip_bfloat16* __restrict__ nechunk,
                          const int* __restrict__ ids,
                          float* __restrict__ sums, int rb, int ch) {
  int g = blockIdx.x;
  int k = threadIdx.x;
  int lo = 0, hi = N_NODES;
  while (lo < hi) { int m = (lo + hi) >> 1; if (ids[m] < g) lo = m + 1; else hi = m; }
  int s = lo;
  hi = N_NODES;
  while (lo < hi) { int m = (lo + hi) >> 1; if (ids[m] < g + 1) lo = m + 1; else hi = m; }
  int e = lo;
  int s2 = s > rb ? s : rb;
  int e2 = e < rb + ch ? e : rb + ch;
  float acc = 0.f;
  for (int r = s2; r < e2; ++r)
    acc += bf2f(nechunk[(size_t)(r - rb) * 256 + k]);
  if (FIRST) sums[g * 256 + k] = acc;
  else if (e2 > s2) sums[g * 256 + k] += acc;
}

__global__ void sigma_fin(const float* __restrict__ sums,
                          const int* __restrict__ ids,
                          __hip_bfloat16* __restrict__ sigma) {
  int g = blockIdx.x;
  int k = threadIdx.x;
  int lo = 0, hi = N_NODES;
  while (lo < hi) { int m = (lo + hi) >> 1; if (ids[m] < g) lo = m + 1; else hi = m; }
  int s = lo;
  hi = N_NODES;
  while (lo < hi) { int m = (lo + hi) >> 1; if (ids[m] < g + 1) lo = m + 1; else hi = m; }
  int e = lo;
  float c = (float)(e - s);
  sigma[g * 256 + k] = __float2bfloat16(sums[g * 256 + k] / fmaxf(c, 1.f));
}

// Fused GEMM: out[M,P] = act(A[M,K] @ BT[P,K]^T + bias (+ extra[bids[row]]))
// 128x128 tile, 4 waves (2x2 of 64x64), BK=64, mfma_f32_16x16x32_bf16.
// global_load_lds width=16 staging; XOR swizzle via pre-swizzled global source
// (LDS dest stays linear: wave-uniform base + lane*16).
template<int ACT, int BF16OUT, int ADD_EXTRA>
__global__ __launch_bounds__(256)
void gemm_mfma(const __hip_bfloat16* __restrict__ A,
               const __hip_bfloat16* __restrict__ BT,
               const float* __restrict__ bias,
               const float* __restrict__ extra,
               const int* __restrict__ bids,
               void* __restrict__ out,
               int K, int P) {
  __shared__ __attribute__((aligned(128))) char smem[32768];
  char* smemA = smem;
  char* smemB = smem + 16384;

  const int tid  = threadIdx.x;
  const int lane = tid & 63;
  const int wave = tid >> 6;
  const int brow = blockIdx.x << 7;
  const int bcol = blockIdx.y << 7;
  const int wm = (wave >> 1) << 6;
  const int wn = (wave & 1) << 6;

  const int rsub = lane >> 3;           // row within 8-row segment
  const int csrc = (lane & 7) ^ rsub;   // pre-swizzled source 16B-chunk

  f32x4 acc[4][4] = {};

  for (int k0 = 0; k0 < K; k0 += 64) {
    if (k0) __syncthreads();   // previous tile fully consumed
#pragma unroll
    for (int i = 0; i < 4; ++i) {
      int seg = (wave << 2) + i;        // 0..15 -> tile rows seg*8..seg*8+7
      int row = (seg << 3) + rsub;
      const __hip_bfloat16* gpA = A + (size_t)(brow + row) * K + (k0 + (csrc << 3));
      __builtin_amdgcn_global_load_lds(
          (const __attribute__((address_space(1))) void*)gpA,
          (__attribute__((address_space(3))) void*)(smemA + (seg << 10)),
          16, 0, 0);
      const __hip_bfloat16* gpB = BT + (size_t)(bcol + row) * K + (k0 + (csrc << 3));
      __builtin_amdgcn_global_load_lds(
          (const __attribute__((address_space(1))) void*)gpB,
          (__attribute__((address_space(3))) void*)(smemB + (seg << 10)),
          16, 0, 0);
    }
    __syncthreads();   // compiler drains vmcnt before barrier

    const int r15 = lane & 15;
#pragma unroll
    for (int ks = 0; ks < 2; ++ks) {
      const int c = (ks << 2) + (lane >> 4);  // logical k-chunk 0..7
      bf16x8 af[4], bfv[4];
#pragma unroll
      for (int f = 0; f < 4; ++f) {
        int ar = wm + (f << 4) + r15;
        af[f]  = *reinterpret_cast<const bf16x8*>(smemA + ar * 128 + ((c ^ (ar & 7)) << 4));
        int br = wn + (f << 4) + r15;
        bfv[f] = *reinterpret_cast<const bf16x8*>(smemB + br * 128 + ((c ^ (br & 7)) << 4));
      }
#pragma unroll
      for (int fm = 0; fm < 4; ++fm)
#pragma unroll
        for (int fn = 0; fn < 4; ++fn)
          acc[fm][fn] = __builtin_amdgcn_mfma_f32_16x16x32_bf16(af[fm], bfv[fn], acc[fm][fn], 0, 0, 0);
    }
  }

  // epilogue: C/D layout col=lane&15, row=(lane>>4)*4+reg   [m89-verified]
  const int r15 = lane & 15;
  const int hi4 = (lane >> 4) << 2;
#pragma unroll
  for (int fn = 0; fn < 4; ++fn) {
    int col = bcol + wn + (fn << 4) + r15;
    float bv = bias[col];
#pragma unroll
    for (int fm = 0; fm < 4; ++fm) {
      int row0 = brow + wm + (fm << 4) + hi4;
#pragma unroll
      for (int r = 0; r < 4; ++r) {
        float v = acc[fm][fn][r] + bv;
        if (ADD_EXTRA) {
          int b = bids[row0 + r];
          v += extra[(size_t)b * P + col];
        }
        if (ACT) v = lrelu_f(v);
        size_t oidx = (size_t)(row0 + r) * P + col;
        if (BF16OUT) reinterpret_cast<__hip_bfloat16*>(out)[oidx] = __float2bfloat16(v);
        else         reinterpret_cast<float*>(out)[oidx] = v;
      }
    }
  }
}

extern "C" void kernel_launch(void* const* d_in, const int* in_sizes, int n_in,
                              void* d_out, int out_size, void* d_ws, size_t ws_size,
                              hipStream_t stream) {
  const float* x      = (const float*)d_in[0];
  const int*   bids   = (const int*)  d_in[1];
  const float* ge_W0  = (const float*)d_in[2];
  const float* ge_b0  = (const float*)d_in[3];
  const float* ge_Wh  = (const float*)d_in[4];
  const float* ge_bh  = (const float*)d_in[5];
  const float* ge_Wo  = (const float*)d_in[6];
  const float* ge_bo  = (const float*)d_in[7];
  const float* in_W   = (const float*)d_in[8];
  const float* in_b   = (const float*)d_in[9];
  const float* ag_W   = (const float*)d_in[10];
  const float* ag_b   = (const float*)d_in[11];
  const float* psi_Wh = (const float*)d_in[12];
  const float* psi_bh = (const float*)d_in[13];
  const float* psi_Wo = (const float*)d_in[14];
  const float* psi_bo = (const float*)d_in[15];

  char* ws = (char*)d_ws;
  __hip_bfloat16* geW0T   = (__hip_bfloat16*)(ws + 0);        // [512][128]
  __hip_bfloat16* geWh0T  = (__hip_bfloat16*)(ws + 131072);   // [512][512]
  __hip_bfloat16* geWh1T  = (__hip_bfloat16*)(ws + 655360);   // [512][512]
  __hip_bfloat16* geWoT   = (__hip_bfloat16*)(ws + 1179648);  // [256][512]
  __hip_bfloat16* inWT    = (__hip_bfloat16*)(ws + 1441792);  // [512][128]
  __hip_bfloat16* agWT    = (__hip_bfloat16*)(ws + 1572864);  // [512][256]
  __hip_bfloat16* psiWh0T = (__hip_bfloat16*)(ws + 1835008);  // [512][512]
  __hip_bfloat16* psiWh1T = (__hip_bfloat16*)(ws + 2359296);  // [512][512]
  __hip_bfloat16* psiWh2T = (__hip_bfloat16*)(ws + 2883584);  // [512][512]
  __hip_bfloat16* psiWoT  = (__hip_bfloat16*)(ws + 3407872);  // [128][512]
  __hip_bfloat16* sigma   = (__hip_bfloat16*)(ws + 3538944);  // [1024][256] bf16
  float*          sh      = (float*)         (ws + 4063232);  // [1024][512] f32
  float*          sums    = (float*)         (ws + 6160384);  // [1024][256] f32
  const size_t base = 7340032;  // 7 MiB

  size_t CH = 0;
  {
    const size_t cands[10] = {65536, 32768, 16384, 8192, 4096, 2048, 1024, 512, 256, 128};
    for (int i = 0; i < 10; ++i)
      if (ws_size >= base + cands[i] * 2304ull) { CH = cands[i]; break; }
  }
  if (CH == 0) {
    sentinel<<<1, 64, 0, stream>>>((float*)d_out, 100000000.f + (float)(ws_size / 1024));
    return;
  }

  __hip_bfloat16* xc  = (__hip_bfloat16*)(ws + base);
  __hip_bfloat16* pp0 = (__hip_bfloat16*)(ws + base + CH * 256);
  __hip_bfloat16* pp1 = (__hip_bfloat16*)(ws + base + CH * 256 + CH * 1024);

  dim3 blk(256);
  const int nch = (int)(N_NODES / CH);
  dim3 g4((unsigned)(CH >> 7), 4), g2((unsigned)(CH >> 7), 2), g1((unsigned)(CH >> 7), 1);

  // ---- weight conversions (all ten) ----
  wt_conv<<<256,  blk, 0, stream>>>(ge_W0,            geW0T,   128, 512);
  wt_conv<<<1024, blk, 0, stream>>>(ge_Wh,            geWh0T,  512, 512);
  wt_conv<<<1024, blk, 0, stream>>>(ge_Wh + 262144,   geWh1T,  512, 512);
  wt_conv<<<512,  blk, 0, stream>>>(ge_Wo,            geWoT,   512, 256);
  wt_conv<<<256,  blk, 0, stream>>>(in_W,             inWT,    128, 512);
  wt_conv<<<512,  blk, 0, stream>>>(ag_W,             agWT,    256, 512);
  wt_conv<<<1024, blk, 0, stream>>>(psi_Wh,           psiWh0T, 512, 512);
  wt_conv<<<1024, blk, 0, stream>>>(psi_Wh + 262144,  psiWh1T, 512, 512);
  wt_conv<<<1024, blk, 0, stream>>>(psi_Wh + 524288,  psiWh2T, 512, 512);
  wt_conv<<<256,  blk, 0, stream>>>(psi_Wo,           psiWoT,  512, 128);

  for (int c = 0; c < nch; ++c) {
    const size_t rb = (size_t)c * CH;
    xconv<<<(unsigned)(CH >> 3), blk, 0, stream>>>(x + rb * 128, xc, (int)(CH * 32));
    gemm_mfma<1,1,0><<<g4, blk, 0, stream>>>(xc,  geW0T,  ge_b0,     nullptr, nullptr, pp0, 128, 512);
    gemm_mfma<1,1,0><<<g4, blk, 0, stream>>>(pp0, geWh0T, ge_bh,     nullptr, nullptr, pp1, 512, 512);
    gemm_mfma<1,1,0><<<g4, blk, 0, stream>>>(pp1, geWh1T, ge_bh+512, nullptr, nullptr, pp0, 512, 512);
    gemm_mfma<1,1,0><<<g2, blk, 0, stream>>>(pp0, geWoT,  ge_bo,     nullptr, nullptr, pp1, 512, 256);
    if (c == 0) seg_accum<1><<<NUM_G, blk, 0, stream>>>(pp1, bids, sums, (int)rb, (int)CH);
    else        seg_accum<0><<<NUM_G, blk, 0, stream>>>(pp1, bids, sums, (int)rb, (int)CH);
  }

  sigma_fin<<<NUM_G, blk, 0, stream>>>(sums, bids, sigma);
  gemm_mfma<0,0,0><<<dim3(8,4), blk, 0, stream>>>(sigma, agWT, ag_b, nullptr, nullptr, sh, 256, 512);

  for (int c = 0; c < nch; ++c) {
    const size_t rb = (size_t)c * CH;
    xconv<<<(unsigned)(CH >> 3), blk, 0, stream>>>(x + rb * 128, xc, (int)(CH * 32));
    gemm_mfma<1,1,1><<<g4, blk, 0, stream>>>(xc,  inWT,    in_b,        sh,      bids + rb, pp0, 128, 512);
    gemm_mfma<1,1,0><<<g4, blk, 0, stream>>>(pp0, psiWh0T, psi_bh,      nullptr, nullptr,   pp1, 512, 512);
    gemm_mfma<1,1,0><<<g4, blk, 0, stream>>>(pp1, psiWh1T, psi_bh+512,  nullptr, nullptr,   pp0, 512, 512);
    gemm_mfma<1,1,0><<<g4, blk, 0, stream>>>(pp0, psiWh2T, psi_bh+1024, nullptr, nullptr,   pp1, 512, 512);
    gemm_mfma<0,0,0><<<g1, blk, 0, stream>>>(pp1, psiWoT,  psi_bo,      nullptr, nullptr,
                                             (float*)d_out + rb * 128, 512, 128);
  }
}